// Round 2
// baseline (595.329 us; speedup 1.0000x reference)
//
#include <hip/hip_runtime.h>

#define E_TOTAL 800000
#define N_TOTAL 50000
#define NBINS   50176   // 196*256, padded

typedef __attribute__((ext_vector_type(8))) short short8;
typedef __attribute__((ext_vector_type(4))) float floatx4;

__device__ __forceinline__ unsigned short f2bf(float f) {
    union { float f; unsigned u; } x; x.f = f;
    unsigned r = x.u + 0x7fff + ((x.u >> 16) & 1);   // RNE
    return (unsigned short)(r >> 16);
}

// ---------------- fused prep: weight transpose + mi zero + h->bf16 + hist zero ----------------
// blocks [0,400): weight transpose+cvt; [400,6650): zero mi; [6650,9775): h->bf16;
// [9775,9971): zero hist
__global__ __launch_bounds__(256)
void prep(const float* __restrict__ We1, const float* __restrict__ We2,
          const float* __restrict__ Wh1, const float* __restrict__ Wh2,
          unsigned short* __restrict__ W1t, unsigned short* __restrict__ W2t,
          unsigned short* __restrict__ Wh1t, unsigned short* __restrict__ Wh2t,
          const float* __restrict__ h, unsigned short* __restrict__ hbf, int do_full,
          float* __restrict__ mi, int* __restrict__ hist)
{
    const int b = blockIdx.x;
    const int tid = threadIdx.x;
    if (b < 400) {
        int t = b * 256 + tid;
        if (t < 36864) {
            W1t[(t & 127) * 288 + (t >> 7)] = f2bf(We1[t]);
        } else if (t < 53248) {
            t -= 36864;
            W2t[(t & 127) * 128 + (t >> 7)] = f2bf(We2[t]);
        } else if (t < 86016) {
            t -= 53248;
            Wh1t[(t & 127) * 256 + (t >> 7)] = f2bf(Wh1[t]);
        } else if (t < 102400) {
            t -= 86016;
            Wh2t[(t & 127) * 128 + (t >> 7)] = f2bf(Wh2[t]);
        }
    } else if (b < 6650) {
        const int t = (b - 400) * 256 + tid;
        ((float4*)mi)[t] = make_float4(0.f, 0.f, 0.f, 0.f);
    } else if (b < 9775) {
        if (do_full) {
            const int t = (b - 6650) * 256 + tid;
            const float4* h4 = (const float4*)h;
            float4 a = h4[(size_t)t * 2];
            float4 c = h4[(size_t)t * 2 + 1];
            short8 v = { (short)f2bf(a.x), (short)f2bf(a.y), (short)f2bf(a.z), (short)f2bf(a.w),
                         (short)f2bf(c.x), (short)f2bf(c.y), (short)f2bf(c.z), (short)f2bf(c.w) };
            *(short8*)(&hbf[(size_t)t * 8]) = v;
        }
    } else {
        if (do_full) hist[(b - 9775) * 256 + tid] = 0;
    }
}

// ---------------- counting sort of edge ids by dst ----------------
__global__ __launch_bounds__(256) void k_hist(const int* __restrict__ ei, int* __restrict__ hist) {
    const int t = blockIdx.x * 256 + threadIdx.x;
    atomicAdd(&hist[ei[E_TOTAL + t]], 1);
}
__global__ __launch_bounds__(256) void k_scan1(const int* __restrict__ hist, int* __restrict__ partial) {
    __shared__ int s[256];
    s[threadIdx.x] = hist[blockIdx.x * 256 + threadIdx.x];
    __syncthreads();
    for (int off = 128; off > 0; off >>= 1) {
        if (threadIdx.x < off) s[threadIdx.x] += s[threadIdx.x + off];
        __syncthreads();
    }
    if (threadIdx.x == 0) partial[blockIdx.x] = s[0];
}
__global__ void k_scan2(int* __restrict__ partial, int* __restrict__ partialOff) {
    if (threadIdx.x == 0) {
        int run = 0;
        for (int i = 0; i < NBINS / 256; ++i) { partialOff[i] = run; run += partial[i]; }
    }
}
__global__ __launch_bounds__(256)
void k_scan3(const int* __restrict__ hist, const int* __restrict__ partialOff,
             int* __restrict__ cursor) {
    __shared__ int s[256];
    const int t = threadIdx.x, g = blockIdx.x * 256 + t;
    const int v = hist[g];
    s[t] = v; __syncthreads();
    for (int off = 1; off < 256; off <<= 1) {
        int x = (t >= off) ? s[t - off] : 0;
        __syncthreads();
        s[t] += x;
        __syncthreads();
    }
    cursor[g] = partialOff[blockIdx.x] + s[t] - v;   // exclusive prefix
}
__global__ __launch_bounds__(256)
void k_scatter(const int* __restrict__ ei, int* __restrict__ cursor, int* __restrict__ perm) {
    const int t = blockIdx.x * 256 + threadIdx.x;
    const int dst = ei[E_TOTAL + t];
    const int pos = atomicAdd(&cursor[dst], 1);
    perm[pos] = t;
}

// ================= MFMA kernels =================
constexpr int XK = 296;  // 288 + 8 pad
constexpr int HK = 136;  // 128 + 8 pad
constexpr int NK = 264;  // 256 + 8 pad
constexpr int FJ = 132;  // fp32 epilogue tile stride

// ---- sorted edge kernel: 64 sorted edges/block, 512 threads, run-reduced scatter ----
// 8 waves = 2 row-groups (32 rows) x 4 col-groups (32 cols). LDS 37.9 KB -> 4 blk/CU
// = 32 waves/CU (same occupancy as old 32-edge/256-thr version) but half the
// W1t/W2t L2 re-streaming and half the per-block fixed overhead.
__global__ __launch_bounds__(512, 8)
void edge_mfma_sorted(const unsigned short* __restrict__ hbf,
                      const int* __restrict__ ei,
                      const float* __restrict__ ea,
                      const int* __restrict__ perm,
                      const unsigned short* __restrict__ W1t,  // [128][288]
                      const float* __restrict__ b1,
                      const unsigned short* __restrict__ W2t,  // [128][128]
                      const float* __restrict__ b2,
                      float* __restrict__ mi)
{
    __shared__ alignas(16) unsigned short sMem[64 * XK];  // aliased: sX / sH / sF
    __shared__ int sDst[64];
    __shared__ int sPerm[64];

    const int tid = threadIdx.x;
    const int e0  = blockIdx.x * 64;
    if (tid < 64) {
        const int p = perm[e0 + tid];
        sPerm[tid] = p;
        sDst[tid]  = ei[E_TOTAL + p];
    }
    __syncthreads();

    const short8* hbf8 = (const short8*)hbf;
    const float4* ea4  = (const float4*)ea;
    #pragma unroll
    for (int it = 0; it < 5; ++it) {
        const int idx = tid + it * 512;        // 64*40 chunks
        const int e  = idx / 40;
        const int c  = idx - e * 40;
        const int ep = sPerm[e];
        if (c < 32) {
            const int node = (c < 16) ? ei[ep] : sDst[e];
            const int cc = c & 15;
            short8 v = hbf8[(size_t)node * 16 + cc];
            *(short8*)(&sMem[e * XK + c * 8]) = v;
        } else {
            float4 x = ea4[(size_t)ep * 8 + (c - 32)];
            unsigned short* p = &sMem[e * XK + 128 + c * 4];
            p[0] = f2bf(x.x); p[1] = f2bf(x.y); p[2] = f2bf(x.z); p[3] = f2bf(x.w);
        }
    }
    __syncthreads();

    const int lane = tid & 63;
    const int w    = tid >> 6;          // 0..7
    const int q    = lane >> 4;
    const int lr   = lane & 15;
    const int n0   = (w & 3) * 32;      // column group
    const int m0   = (w >> 2) * 32;     // row group

    // ---- GEMM1 ----
    floatx4 acc[2][2];
    #pragma unroll
    for (int mt = 0; mt < 2; ++mt)
        #pragma unroll
        for (int nt = 0; nt < 2; ++nt)
            acc[mt][nt] = (floatx4){0.f, 0.f, 0.f, 0.f};

    #pragma unroll
    for (int ks = 0; ks < 9; ++ks) {
        const int kb = ks * 32 + q * 8;
        short8 a[2], b[2];
        #pragma unroll
        for (int mt = 0; mt < 2; ++mt)
            a[mt] = *(const short8*)(&sMem[(m0 + mt * 16 + lr) * XK + kb]);
        #pragma unroll
        for (int nt = 0; nt < 2; ++nt)
            b[nt] = *(const short8*)(&W1t[(n0 + nt * 16 + lr) * 288 + kb]);
        #pragma unroll
        for (int mt = 0; mt < 2; ++mt)
            #pragma unroll
            for (int nt = 0; nt < 2; ++nt)
                acc[mt][nt] = __builtin_amdgcn_mfma_f32_16x16x32_bf16(
                    a[mt], b[nt], acc[mt][nt], 0, 0, 0);
    }
    __syncthreads();

    {
        float bias[2] = { b1[n0 + lr], b1[n0 + 16 + lr] };
        #pragma unroll
        for (int mt = 0; mt < 2; ++mt)
            #pragma unroll
            for (int nt = 0; nt < 2; ++nt)
                #pragma unroll
                for (int r = 0; r < 4; ++r) {
                    float v = fmaxf(acc[mt][nt][r] + bias[nt], 0.f);
                    sMem[(m0 + mt * 16 + q * 4 + r) * HK + n0 + nt * 16 + lr] = f2bf(v);
                }
    }
    __syncthreads();

    // ---- GEMM2 ----
    floatx4 acc2[2][2];
    #pragma unroll
    for (int mt = 0; mt < 2; ++mt)
        #pragma unroll
        for (int nt = 0; nt < 2; ++nt)
            acc2[mt][nt] = (floatx4){0.f, 0.f, 0.f, 0.f};

    #pragma unroll
    for (int ks = 0; ks < 4; ++ks) {
        const int kb = ks * 32 + q * 8;
        short8 a[2], b[2];
        #pragma unroll
        for (int mt = 0; mt < 2; ++mt)
            a[mt] = *(const short8*)(&sMem[(m0 + mt * 16 + lr) * HK + kb]);
        #pragma unroll
        for (int nt = 0; nt < 2; ++nt)
            b[nt] = *(const short8*)(&W2t[(n0 + nt * 16 + lr) * 128 + kb]);
        #pragma unroll
        for (int mt = 0; mt < 2; ++mt)
            #pragma unroll
            for (int nt = 0; nt < 2; ++nt)
                acc2[mt][nt] = __builtin_amdgcn_mfma_f32_16x16x32_bf16(
                    a[mt], b[nt], acc2[mt][nt], 0, 0, 0);
    }
    __syncthreads();   // GEMM2 LDS reads done before fp32 tile overwrite

    // ---- m_ij tile -> LDS (fp32), then run-length-reduced atomics ----
    float* sF = (float*)sMem;   // [64][FJ]
    {
        float bias[2] = { b2[n0 + lr], b2[n0 + 16 + lr] };
        #pragma unroll
        for (int mt = 0; mt < 2; ++mt)
            #pragma unroll
            for (int nt = 0; nt < 2; ++nt)
                #pragma unroll
                for (int r = 0; r < 4; ++r)
                    sF[(m0 + mt * 16 + q * 4 + r) * FJ + n0 + nt * 16 + lr] =
                        acc2[mt][nt][r] + bias[nt];
    }
    __syncthreads();

    {
        // 512 threads: 4 groups of 128 lanes, each reduces 16 sorted rows.
        // Runs crossing a group boundary flush twice (atomic add is associative).
        const int g  = tid >> 7;        // 0..3
        const int j  = tid & 127;
        const int r0 = g * 16;
        float sum = 0.f;
        for (int r = r0; r < r0 + 16; ++r) {
            sum += sF[r * FJ + j];
            const int dst = sDst[r];
            if (r == r0 + 15 || sDst[r + 1] != dst) {   // wave-uniform branch
                atomicAdd(&mi[(size_t)dst * 128 + j], sum);
                sum = 0.f;
            }
        }
    }
}

// ---- flat fallback edge kernel (round-4) ----
template <bool PRECVT>
__global__ __launch_bounds__(256, 8)
void edge_mfma_flat(const float* __restrict__ h,
                    const unsigned short* __restrict__ hbf,
                    const int* __restrict__ ei,
                    const float* __restrict__ ea,
                    const unsigned short* __restrict__ W1t,
                    const float* __restrict__ b1,
                    const unsigned short* __restrict__ W2t,
                    const float* __restrict__ b2,
                    float* __restrict__ mi)
{
    __shared__ unsigned short sMem[32 * XK];
    __shared__ int sDst[32];

    const int tid = threadIdx.x;
    const int e0  = blockIdx.x * 32;
    if (tid < 32) sDst[tid] = ei[E_TOTAL + e0 + tid];

    const float4* h4   = (const float4*)h;
    const short8* hbf8 = (const short8*)hbf;
    const float4* ea4  = (const float4*)ea;
    #pragma unroll
    for (int it = 0; it < 5; ++it) {
        const int idx = tid + it * 256;
        const int e  = idx / 40;
        const int c  = idx - e * 40;
        const int ge = e0 + e;
        if (c < 32) {
            const int node = (c < 16) ? ei[ge] : ei[E_TOTAL + ge];
            const int cc = c & 15;
            short8 v;
            if (PRECVT) {
                v = hbf8[(size_t)node * 16 + cc];
            } else {
                float4 x = h4[(size_t)node * 32 + cc * 2];
                float4 y = h4[(size_t)node * 32 + cc * 2 + 1];
                v = (short8){ (short)f2bf(x.x), (short)f2bf(x.y), (short)f2bf(x.z), (short)f2bf(x.w),
                              (short)f2bf(y.x), (short)f2bf(y.y), (short)f2bf(y.z), (short)f2bf(y.w) };
            }
            *(short8*)(&sMem[e * XK + c * 8]) = v;
        } else {
            float4 x = ea4[(size_t)ge * 8 + (c - 32)];
            unsigned short* p = &sMem[e * XK + 128 + c * 4];
            p[0] = f2bf(x.x); p[1] = f2bf(x.y); p[2] = f2bf(x.z); p[3] = f2bf(x.w);
        }
    }
    __syncthreads();

    const int lane = tid & 63;
    const int w    = tid >> 6;
    const int q    = lane >> 4;
    const int lr   = lane & 15;
    const int n0   = w * 32;

    floatx4 acc[2][2];
    #pragma unroll
    for (int mt = 0; mt < 2; ++mt)
        #pragma unroll
        for (int nt = 0; nt < 2; ++nt)
            acc[mt][nt] = (floatx4){0.f, 0.f, 0.f, 0.f};
    #pragma unroll
    for (int ks = 0; ks < 9; ++ks) {
        const int kb = ks * 32 + q * 8;
        short8 a[2], b[2];
        #pragma unroll
        for (int mt = 0; mt < 2; ++mt)
            a[mt] = *(const short8*)(&sMem[(mt * 16 + lr) * XK + kb]);
        #pragma unroll
        for (int nt = 0; nt < 2; ++nt)
            b[nt] = *(const short8*)(&W1t[(n0 + nt * 16 + lr) * 288 + kb]);
        #pragma unroll
        for (int mt = 0; mt < 2; ++mt)
            #pragma unroll
            for (int nt = 0; nt < 2; ++nt)
                acc[mt][nt] = __builtin_amdgcn_mfma_f32_16x16x32_bf16(
                    a[mt], b[nt], acc[mt][nt], 0, 0, 0);
    }
    __syncthreads();
    {
        float bias[2] = { b1[n0 + lr], b1[n0 + 16 + lr] };
        #pragma unroll
        for (int mt = 0; mt < 2; ++mt)
            #pragma unroll
            for (int nt = 0; nt < 2; ++nt)
                #pragma unroll
                for (int r = 0; r < 4; ++r) {
                    float v = fmaxf(acc[mt][nt][r] + bias[nt], 0.f);
                    sMem[(mt * 16 + q * 4 + r) * HK + n0 + nt * 16 + lr] = f2bf(v);
                }
    }
    __syncthreads();
    floatx4 acc2[2][2];
    #pragma unroll
    for (int mt = 0; mt < 2; ++mt)
        #pragma unroll
        for (int nt = 0; nt < 2; ++nt)
            acc2[mt][nt] = (floatx4){0.f, 0.f, 0.f, 0.f};
    #pragma unroll
    for (int ks = 0; ks < 4; ++ks) {
        const int kb = ks * 32 + q * 8;
        short8 a[2], b[2];
        #pragma unroll
        for (int mt = 0; mt < 2; ++mt)
            a[mt] = *(const short8*)(&sMem[(mt * 16 + lr) * HK + kb]);
        #pragma unroll
        for (int nt = 0; nt < 2; ++nt)
            b[nt] = *(const short8*)(&W2t[(n0 + nt * 16 + lr) * 128 + kb]);
        #pragma unroll
        for (int mt = 0; mt < 2; ++mt)
            #pragma unroll
            for (int nt = 0; nt < 2; ++nt)
                acc2[mt][nt] = __builtin_amdgcn_mfma_f32_16x16x32_bf16(
                    a[mt], b[nt], acc2[mt][nt], 0, 0, 0);
    }
    {
        float bias[2] = { b2[n0 + lr], b2[n0 + 16 + lr] };
        #pragma unroll
        for (int mt = 0; mt < 2; ++mt)
            #pragma unroll
            for (int r = 0; r < 4; ++r) {
                const int m   = mt * 16 + q * 4 + r;
                const int dst = sDst[m];
                float* row = &mi[(size_t)dst * 128];
                #pragma unroll
                for (int nt = 0; nt < 2; ++nt)
                    atomicAdd(&row[n0 + nt * 16 + lr], acc2[mt][nt][r] + bias[nt]);
            }
    }
}

// ---- node kernel (unchanged) ----
__global__ __launch_bounds__(256, 8)
void node_mfma(const float* __restrict__ h,
               const float* __restrict__ mi,
               const unsigned short* __restrict__ W1t,
               const float* __restrict__ b1,
               const unsigned short* __restrict__ W2t,
               const float* __restrict__ b2,
               float* __restrict__ out)
{
    __shared__ unsigned short sMem[32 * NK];

    const int tid = threadIdx.x;
    const int g0  = blockIdx.x * 32;

    const float4* h4  = (const float4*)h;
    const float4* mi4 = (const float4*)mi;
    #pragma unroll
    for (int it = 0; it < 8; ++it) {
        const int idx = tid + it * 256;
        const int n  = idx >> 6;
        const int c  = idx & 63;
        const int gn = g0 + n;
        float4 v = make_float4(0.f, 0.f, 0.f, 0.f);
        if (gn < N_TOTAL)
            v = (c < 32) ? h4[(size_t)gn * 32 + c] : mi4[(size_t)gn * 32 + (c - 32)];
        unsigned short* p = &sMem[n * NK + c * 4];
        p[0] = f2bf(v.x); p[1] = f2bf(v.y); p[2] = f2bf(v.z); p[3] = f2bf(v.w);
    }
    __syncthreads();

    const int lane = tid & 63;
    const int w    = tid >> 6;
    const int q    = lane >> 4;
    const int lr   = lane & 15;
    const int n0   = w * 32;

    floatx4 acc[2][2];
    #pragma unroll
    for (int mt = 0; mt < 2; ++mt)
        #pragma unroll
        for (int nt = 0; nt < 2; ++nt)
            acc[mt][nt] = (floatx4){0.f, 0.f, 0.f, 0.f};
    #pragma unroll
    for (int ks = 0; ks < 8; ++ks) {
        const int kb = ks * 32 + q * 8;
        short8 a[2], b[2];
        #pragma unroll
        for (int mt = 0; mt < 2; ++mt)
            a[mt] = *(const short8*)(&sMem[(mt * 16 + lr) * NK + kb]);
        #pragma unroll
        for (int nt = 0; nt < 2; ++nt)
            b[nt] = *(const short8*)(&W1t[(n0 + nt * 16 + lr) * 256 + kb]);
        #pragma unroll
        for (int mt = 0; mt < 2; ++mt)
            #pragma unroll
            for (int nt = 0; nt < 2; ++nt)
                acc[mt][nt] = __builtin_amdgcn_mfma_f32_16x16x32_bf16(
                    a[mt], b[nt], acc[mt][nt], 0, 0, 0);
    }
    __syncthreads();
    {
        float bias[2] = { b1[n0 + lr], b1[n0 + 16 + lr] };
        #pragma unroll
        for (int mt = 0; mt < 2; ++mt)
            #pragma unroll
            for (int nt = 0; nt < 2; ++nt)
                #pragma unroll
                for (int r = 0; r < 4; ++r) {
                    float v = fmaxf(acc[mt][nt][r] + bias[nt], 0.f);
                    sMem[(mt * 16 + q * 4 + r) * HK + n0 + nt * 16 + lr] = f2bf(v);
                }
    }
    __syncthreads();
    floatx4 acc2[2][2];
    #pragma unroll
    for (int mt = 0; mt < 2; ++mt)
        #pragma unroll
        for (int nt = 0; nt < 2; ++nt)
            acc2[mt][nt] = (floatx4){0.f, 0.f, 0.f, 0.f};
    #pragma unroll
    for (int ks = 0; ks < 4; ++ks) {
        const int kb = ks * 32 + q * 8;
        short8 a[2], b[2];
        #pragma unroll
        for (int mt = 0; mt < 2; ++mt)
            a[mt] = *(const short8*)(&sMem[(mt * 16 + lr) * HK + kb]);
        #pragma unroll
        for (int nt = 0; nt < 2; ++nt)
            b[nt] = *(const short8*)(&W2t[(n0 + nt * 16 + lr) * 128 + kb]);
        #pragma unroll
        for (int mt = 0; mt < 2; ++mt)
            #pragma unroll
            for (int nt = 0; nt < 2; ++nt)
                acc2[mt][nt] = __builtin_amdgcn_mfma_f32_16x16x32_bf16(
                    a[mt], b[nt], acc2[mt][nt], 0, 0, 0);
    }
    {
        float bias[2] = { b2[n0 + lr], b2[n0 + 16 + lr] };
        #pragma unroll
        for (int mt = 0; mt < 2; ++mt)
            #pragma unroll
            for (int r = 0; r < 4; ++r) {
                const int gm = g0 + mt * 16 + q * 4 + r;
                if (gm < N_TOTAL) {
                    #pragma unroll
                    for (int nt = 0; nt < 2; ++nt)
                        out[(size_t)gm * 128 + n0 + nt * 16 + lr] =
                            acc2[mt][nt][r] + bias[nt];
                }
            }
    }
}

extern "C" void kernel_launch(void* const* d_in, const int* in_sizes, int n_in,
                              void* d_out, int out_size, void* d_ws, size_t ws_size,
                              hipStream_t stream) {
    const float* h   = (const float*)d_in[0];
    const int*   ei  = (const int*)d_in[1];
    const float* ea  = (const float*)d_in[2];
    const float* We1 = (const float*)d_in[3];
    const float* be1 = (const float*)d_in[4];
    const float* We2 = (const float*)d_in[5];
    const float* be2 = (const float*)d_in[6];
    const float* Wh1 = (const float*)d_in[7];
    const float* bh1 = (const float*)d_in[8];
    const float* Wh2 = (const float*)d_in[9];
    const float* bh2 = (const float*)d_in[10];
    float* out = (float*)d_out;

    const size_t szMi   = (size_t)N_TOTAL * 128 * sizeof(float);
    const size_t szW1t  = 128 * 288 * 2;
    const size_t szW2t  = 128 * 128 * 2;
    const size_t szWh1t = 128 * 256 * 2;
    const size_t szWh2t = 128 * 128 * 2;
    const size_t szHbf  = (size_t)N_TOTAL * 128 * 2;
    const size_t szPerm = (size_t)E_TOTAL * 4;
    const size_t szHist = (size_t)NBINS * 4;

    const size_t offW1t  = szMi;
    const size_t offW2t  = offW1t + szW1t;
    const size_t offWh1t = offW2t + szW2t;
    const size_t offWh2t = offWh1t + szWh1t;
    const size_t offHbf  = offWh2t + szWh2t;
    const size_t offPerm = offHbf + szHbf;
    const size_t offHist = offPerm + szPerm;
    const size_t offCur  = offHist + szHist;
    const size_t offP1   = offCur + szHist;
    const size_t offP2   = offP1 + 1024;
    const size_t needFull = offP2 + 1024;
    const size_t needCvt  = offPerm;

    char* wsb = (char*)d_ws;
    float* mi = (float*)wsb;
    unsigned short* W1t  = (unsigned short*)(wsb + offW1t);
    unsigned short* W2t  = (unsigned short*)(wsb + offW2t);
    unsigned short* Wh1t = (unsigned short*)(wsb + offWh1t);
    unsigned short* Wh2t = (unsigned short*)(wsb + offWh2t);
    unsigned short* hbf  = (unsigned short*)(wsb + offHbf);
    int* perm    = (int*)(wsb + offPerm);
    int* hist    = (int*)(wsb + offHist);
    int* cursor  = (int*)(wsb + offCur);
    int* partial = (int*)(wsb + offP1);
    int* poff    = (int*)(wsb + offP2);

    const int full = (ws_size >= needFull) ? 1 : 0;

    prep<<<9971, 256, 0, stream>>>(We1, We2, Wh1, Wh2, W1t, W2t, Wh1t, Wh2t,
                                   h, hbf, full, mi, hist);

    if (full) {
        k_hist<<<E_TOTAL / 256, 256, 0, stream>>>(ei, hist);
        k_scan1<<<NBINS / 256, 256, 0, stream>>>(hist, partial);
        k_scan2<<<1, 64, 0, stream>>>(partial, poff);
        k_scan3<<<NBINS / 256, 256, 0, stream>>>(hist, poff, cursor);
        k_scatter<<<E_TOTAL / 256, 256, 0, stream>>>(ei, cursor, perm);
        edge_mfma_sorted<<<E_TOTAL / 64, 512, 0, stream>>>(
            hbf, ei, ea, perm, W1t, be1, W2t, be2, mi);
    } else if (ws_size >= needCvt + szHbf) {
        // no room for sort buffers but room for hbf
        edge_mfma_flat<true><<<E_TOTAL / 32, 256, 0, stream>>>(
            h, hbf, ei, ea, W1t, be1, W2t, be2, mi);
    } else {
        edge_mfma_flat<false><<<E_TOTAL / 32, 256, 0, stream>>>(
            h, nullptr, ei, ea, W1t, be1, W2t, be2, mi);
    }
    node_mfma<<<(N_TOTAL + 31) / 32, 256, 0, stream>>>(
        h, mi, Wh1t, bh1, Wh2t, bh2, out);
    (void)in_sizes; (void)n_in; (void)out_size;
}

// Round 3
// 590.229 us; speedup vs baseline: 1.0086x; 1.0086x over previous
//
#include <hip/hip_runtime.h>

#define E_TOTAL 800000
#define N_TOTAL 50000
#define NBINS   50176   // 196*256, padded

typedef __attribute__((ext_vector_type(8))) short short8;
typedef __attribute__((ext_vector_type(4))) float floatx4;

__device__ __forceinline__ unsigned short f2bf(float f) {
    union { float f; unsigned u; } x; x.f = f;
    unsigned r = x.u + 0x7fff + ((x.u >> 16) & 1);   // RNE
    return (unsigned short)(r >> 16);
}

// ---------------- fused prep: weight transpose + mi zero + h->bf16 + hist zero ----------------
// blocks [0,400): weight transpose+cvt; [400,6650): zero mi; [6650,9775): h->bf16;
// [9775,9971): zero hist
__global__ __launch_bounds__(256)
void prep(const float* __restrict__ We1, const float* __restrict__ We2,
          const float* __restrict__ Wh1, const float* __restrict__ Wh2,
          unsigned short* __restrict__ W1t, unsigned short* __restrict__ W2t,
          unsigned short* __restrict__ Wh1t, unsigned short* __restrict__ Wh2t,
          const float* __restrict__ h, unsigned short* __restrict__ hbf,
          int do_cvt, int do_sort,
          float* __restrict__ mi, int* __restrict__ hist)
{
    const int b = blockIdx.x;
    const int tid = threadIdx.x;
    if (b < 400) {
        int t = b * 256 + tid;
        if (t < 36864) {
            W1t[(t & 127) * 288 + (t >> 7)] = f2bf(We1[t]);
        } else if (t < 53248) {
            t -= 36864;
            W2t[(t & 127) * 128 + (t >> 7)] = f2bf(We2[t]);
        } else if (t < 86016) {
            t -= 53248;
            Wh1t[(t & 127) * 256 + (t >> 7)] = f2bf(Wh1[t]);
        } else if (t < 102400) {
            t -= 86016;
            Wh2t[(t & 127) * 128 + (t >> 7)] = f2bf(Wh2[t]);
        }
    } else if (b < 6650) {
        const int t = (b - 400) * 256 + tid;
        ((float4*)mi)[t] = make_float4(0.f, 0.f, 0.f, 0.f);
    } else if (b < 9775) {
        if (do_cvt) {
            const int t = (b - 6650) * 256 + tid;
            const float4* h4 = (const float4*)h;
            float4 a = h4[(size_t)t * 2];
            float4 c = h4[(size_t)t * 2 + 1];
            short8 v = { (short)f2bf(a.x), (short)f2bf(a.y), (short)f2bf(a.z), (short)f2bf(a.w),
                         (short)f2bf(c.x), (short)f2bf(c.y), (short)f2bf(c.z), (short)f2bf(c.w) };
            *(short8*)(&hbf[(size_t)t * 8]) = v;
        }
    } else {
        if (do_sort) hist[(b - 9775) * 256 + tid] = 0;
    }
}

// ---------------- counting sort of edge ids by dst ----------------
__global__ __launch_bounds__(256) void k_hist(const int* __restrict__ ei, int* __restrict__ hist) {
    const int t = blockIdx.x * 256 + threadIdx.x;
    atomicAdd(&hist[ei[E_TOTAL + t]], 1);
}
__global__ __launch_bounds__(256) void k_scan1(const int* __restrict__ hist, int* __restrict__ partial) {
    __shared__ int s[256];
    s[threadIdx.x] = hist[blockIdx.x * 256 + threadIdx.x];
    __syncthreads();
    for (int off = 128; off > 0; off >>= 1) {
        if (threadIdx.x < off) s[threadIdx.x] += s[threadIdx.x + off];
        __syncthreads();
    }
    if (threadIdx.x == 0) partial[blockIdx.x] = s[0];
}
// parallel scan over the 196 block partials (was a 1-thread serial loop)
__global__ __launch_bounds__(256)
void k_scan2(const int* __restrict__ partial, int* __restrict__ partialOff) {
    __shared__ int s[256];
    const int t = threadIdx.x;
    const int NP = NBINS / 256;   // 196
    const int v = (t < NP) ? partial[t] : 0;
    s[t] = v; __syncthreads();
    for (int off = 1; off < 256; off <<= 1) {
        int x = (t >= off) ? s[t - off] : 0;
        __syncthreads();
        s[t] += x;
        __syncthreads();
    }
    if (t < NP) partialOff[t] = s[t] - v;   // exclusive prefix
}
__global__ __launch_bounds__(256)
void k_scan3(const int* __restrict__ hist, const int* __restrict__ partialOff,
             int* __restrict__ cursor) {
    __shared__ int s[256];
    const int t = threadIdx.x, g = blockIdx.x * 256 + t;
    const int v = hist[g];
    s[t] = v; __syncthreads();
    for (int off = 1; off < 256; off <<= 1) {
        int x = (t >= off) ? s[t - off] : 0;
        __syncthreads();
        s[t] += x;
        __syncthreads();
    }
    cursor[g] = partialOff[blockIdx.x] + s[t] - v;   // exclusive prefix
}
__global__ __launch_bounds__(256)
void k_scatter(const int* __restrict__ ei, int* __restrict__ cursor, int* __restrict__ perm) {
    const int t = blockIdx.x * 256 + threadIdx.x;
    const int dst = ei[E_TOTAL + t];
    const int pos = atomicAdd(&cursor[dst], 1);
    perm[pos] = t;
}

// ================= MFMA kernels =================
constexpr int XK = 296;  // 288 + 8 pad
constexpr int HK = 136;  // 128 + 8 pad
constexpr int NK = 264;  // 256 + 8 pad
constexpr int FJ = 132;  // fp32 epilogue tile stride

// ---- sorted edge kernel v3: 64 edges/block, 256 threads (4 waves) ----
// Each wave owns a 64-row x 32-col output slab (m-tiles=4, n-tiles=2): W1/W2
// fragments are loaded ONCE per block and reused 4x. __launch_bounds__(256,4)
// gives a 128-VGPR budget so the unrolled K-loops can pipeline W loads instead
// of serializing on L2 latency (v2: 64-VGPR cap -> 28 VGPRs, MfmaUtil 11%).
// LDS 38.4 KB -> 4 blocks/CU = 16 waves/CU.
__global__ __launch_bounds__(256, 4)
void edge_mfma_sorted(const unsigned short* __restrict__ hbf,
                      const int* __restrict__ ei,
                      const float* __restrict__ ea,
                      const int* __restrict__ perm,
                      const unsigned short* __restrict__ W1t,  // [128][288]
                      const float* __restrict__ b1,
                      const unsigned short* __restrict__ W2t,  // [128][128]
                      const float* __restrict__ b2,
                      float* __restrict__ mi)
{
    __shared__ alignas(16) unsigned short sMem[64 * XK];  // aliased: sX / sH / sF
    __shared__ int sDst[64];
    __shared__ int sPerm[64];

    const int tid = threadIdx.x;
    const int e0  = blockIdx.x * 64;
    if (tid < 64) {
        const int p = perm[e0 + tid];
        sPerm[tid] = p;
        sDst[tid]  = ei[E_TOTAL + p];
    }
    __syncthreads();

    const short8* hbf8 = (const short8*)hbf;
    const float4* ea4  = (const float4*)ea;
    #pragma unroll
    for (int it = 0; it < 10; ++it) {
        const int idx = tid + it * 256;        // 64*40 chunks
        const int e  = idx / 40;
        const int c  = idx - e * 40;
        const int ep = sPerm[e];
        if (c < 32) {
            const int node = (c < 16) ? ei[ep] : sDst[e];
            const int cc = c & 15;
            short8 v = hbf8[(size_t)node * 16 + cc];
            *(short8*)(&sMem[e * XK + c * 8]) = v;
        } else {
            float4 x = ea4[(size_t)ep * 8 + (c - 32)];
            unsigned short* p = &sMem[e * XK + 128 + c * 4];
            p[0] = f2bf(x.x); p[1] = f2bf(x.y); p[2] = f2bf(x.z); p[3] = f2bf(x.w);
        }
    }
    __syncthreads();

    const int lane = tid & 63;
    const int w    = tid >> 6;     // 0..3: column group
    const int q    = lane >> 4;
    const int lr   = lane & 15;
    const int n0   = w * 32;

    // ---- GEMM1: 64x288 @ 288x32 ----
    floatx4 acc[4][2];
    #pragma unroll
    for (int mt = 0; mt < 4; ++mt)
        #pragma unroll
        for (int nt = 0; nt < 2; ++nt)
            acc[mt][nt] = (floatx4){0.f, 0.f, 0.f, 0.f};

    #pragma unroll
    for (int ks = 0; ks < 9; ++ks) {
        const int kb = ks * 32 + q * 8;
        short8 a[4], b[2];
        #pragma unroll
        for (int nt = 0; nt < 2; ++nt)
            b[nt] = *(const short8*)(&W1t[(n0 + nt * 16 + lr) * 288 + kb]);
        #pragma unroll
        for (int mt = 0; mt < 4; ++mt)
            a[mt] = *(const short8*)(&sMem[(mt * 16 + lr) * XK + kb]);
        #pragma unroll
        for (int mt = 0; mt < 4; ++mt)
            #pragma unroll
            for (int nt = 0; nt < 2; ++nt)
                acc[mt][nt] = __builtin_amdgcn_mfma_f32_16x16x32_bf16(
                    a[mt], b[nt], acc[mt][nt], 0, 0, 0);
    }
    __syncthreads();

    {
        float bias[2] = { b1[n0 + lr], b1[n0 + 16 + lr] };
        #pragma unroll
        for (int mt = 0; mt < 4; ++mt)
            #pragma unroll
            for (int nt = 0; nt < 2; ++nt)
                #pragma unroll
                for (int r = 0; r < 4; ++r) {
                    float v = fmaxf(acc[mt][nt][r] + bias[nt], 0.f);
                    sMem[(mt * 16 + q * 4 + r) * HK + n0 + nt * 16 + lr] = f2bf(v);
                }
    }
    __syncthreads();

    // ---- GEMM2: 64x128 @ 128x32 ----
    floatx4 acc2[4][2];
    #pragma unroll
    for (int mt = 0; mt < 4; ++mt)
        #pragma unroll
        for (int nt = 0; nt < 2; ++nt)
            acc2[mt][nt] = (floatx4){0.f, 0.f, 0.f, 0.f};

    #pragma unroll
    for (int ks = 0; ks < 4; ++ks) {
        const int kb = ks * 32 + q * 8;
        short8 a[4], b[2];
        #pragma unroll
        for (int nt = 0; nt < 2; ++nt)
            b[nt] = *(const short8*)(&W2t[(n0 + nt * 16 + lr) * 128 + kb]);
        #pragma unroll
        for (int mt = 0; mt < 4; ++mt)
            a[mt] = *(const short8*)(&sMem[(mt * 16 + lr) * HK + kb]);
        #pragma unroll
        for (int mt = 0; mt < 4; ++mt)
            #pragma unroll
            for (int nt = 0; nt < 2; ++nt)
                acc2[mt][nt] = __builtin_amdgcn_mfma_f32_16x16x32_bf16(
                    a[mt], b[nt], acc2[mt][nt], 0, 0, 0);
    }
    __syncthreads();   // GEMM2 LDS reads done before fp32 tile overwrite

    // ---- m_ij tile -> LDS (fp32), then run-length-reduced atomics ----
    float* sF = (float*)sMem;   // [64][FJ]
    {
        float bias[2] = { b2[n0 + lr], b2[n0 + 16 + lr] };
        #pragma unroll
        for (int mt = 0; mt < 4; ++mt)
            #pragma unroll
            for (int nt = 0; nt < 2; ++nt)
                #pragma unroll
                for (int r = 0; r < 4; ++r)
                    sF[(mt * 16 + q * 4 + r) * FJ + n0 + nt * 16 + lr] =
                        acc2[mt][nt][r] + bias[nt];
    }
    __syncthreads();

    {
        // 256 threads: 2 groups of 128 lanes, each reduces 32 sorted rows.
        // Runs crossing a group boundary flush twice (atomic add is associative).
        const int g  = tid >> 7;        // 0..1
        const int j  = tid & 127;
        const int r0 = g * 32;
        float sum = 0.f;
        for (int r = r0; r < r0 + 32; ++r) {
            sum += sF[r * FJ + j];
            const int dst = sDst[r];
            if (r == r0 + 31 || sDst[r + 1] != dst) {   // wave-uniform branch
                atomicAdd(&mi[(size_t)dst * 128 + j], sum);
                sum = 0.f;
            }
        }
    }
}

// ---- flat fallback edge kernel ----
template <bool PRECVT>
__global__ __launch_bounds__(256, 8)
void edge_mfma_flat(const float* __restrict__ h,
                    const unsigned short* __restrict__ hbf,
                    const int* __restrict__ ei,
                    const float* __restrict__ ea,
                    const unsigned short* __restrict__ W1t,
                    const float* __restrict__ b1,
                    const unsigned short* __restrict__ W2t,
                    const float* __restrict__ b2,
                    float* __restrict__ mi)
{
    __shared__ unsigned short sMem[32 * XK];
    __shared__ int sDst[32];

    const int tid = threadIdx.x;
    const int e0  = blockIdx.x * 32;
    if (tid < 32) sDst[tid] = ei[E_TOTAL + e0 + tid];

    const float4* h4   = (const float4*)h;
    const short8* hbf8 = (const short8*)hbf;
    const float4* ea4  = (const float4*)ea;
    #pragma unroll
    for (int it = 0; it < 5; ++it) {
        const int idx = tid + it * 256;
        const int e  = idx / 40;
        const int c  = idx - e * 40;
        const int ge = e0 + e;
        if (c < 32) {
            const int node = (c < 16) ? ei[ge] : ei[E_TOTAL + ge];
            const int cc = c & 15;
            short8 v;
            if (PRECVT) {
                v = hbf8[(size_t)node * 16 + cc];
            } else {
                float4 x = h4[(size_t)node * 32 + cc * 2];
                float4 y = h4[(size_t)node * 32 + cc * 2 + 1];
                v = (short8){ (short)f2bf(x.x), (short)f2bf(x.y), (short)f2bf(x.z), (short)f2bf(x.w),
                              (short)f2bf(y.x), (short)f2bf(y.y), (short)f2bf(y.z), (short)f2bf(y.w) };
            }
            *(short8*)(&sMem[e * XK + c * 8]) = v;
        } else {
            float4 x = ea4[(size_t)ge * 8 + (c - 32)];
            unsigned short* p = &sMem[e * XK + 128 + c * 4];
            p[0] = f2bf(x.x); p[1] = f2bf(x.y); p[2] = f2bf(x.z); p[3] = f2bf(x.w);
        }
    }
    __syncthreads();

    const int lane = tid & 63;
    const int w    = tid >> 6;
    const int q    = lane >> 4;
    const int lr   = lane & 15;
    const int n0   = w * 32;

    floatx4 acc[2][2];
    #pragma unroll
    for (int mt = 0; mt < 2; ++mt)
        #pragma unroll
        for (int nt = 0; nt < 2; ++nt)
            acc[mt][nt] = (floatx4){0.f, 0.f, 0.f, 0.f};
    #pragma unroll
    for (int ks = 0; ks < 9; ++ks) {
        const int kb = ks * 32 + q * 8;
        short8 a[2], b[2];
        #pragma unroll
        for (int mt = 0; mt < 2; ++mt)
            a[mt] = *(const short8*)(&sMem[(mt * 16 + lr) * XK + kb]);
        #pragma unroll
        for (int nt = 0; nt < 2; ++nt)
            b[nt] = *(const short8*)(&W1t[(n0 + nt * 16 + lr) * 288 + kb]);
        #pragma unroll
        for (int mt = 0; mt < 2; ++mt)
            #pragma unroll
            for (int nt = 0; nt < 2; ++nt)
                acc[mt][nt] = __builtin_amdgcn_mfma_f32_16x16x32_bf16(
                    a[mt], b[nt], acc[mt][nt], 0, 0, 0);
    }
    __syncthreads();
    {
        float bias[2] = { b1[n0 + lr], b1[n0 + 16 + lr] };
        #pragma unroll
        for (int mt = 0; mt < 2; ++mt)
            #pragma unroll
            for (int nt = 0; nt < 2; ++nt)
                #pragma unroll
                for (int r = 0; r < 4; ++r) {
                    float v = fmaxf(acc[mt][nt][r] + bias[nt], 0.f);
                    sMem[(mt * 16 + q * 4 + r) * HK + n0 + nt * 16 + lr] = f2bf(v);
                }
    }
    __syncthreads();
    floatx4 acc2[2][2];
    #pragma unroll
    for (int mt = 0; mt < 2; ++mt)
        #pragma unroll
        for (int nt = 0; nt < 2; ++nt)
            acc2[mt][nt] = (floatx4){0.f, 0.f, 0.f, 0.f};
    #pragma unroll
    for (int ks = 0; ks < 4; ++ks) {
        const int kb = ks * 32 + q * 8;
        short8 a[2], b[2];
        #pragma unroll
        for (int mt = 0; mt < 2; ++mt)
            a[mt] = *(const short8*)(&sMem[(mt * 16 + lr) * HK + kb]);
        #pragma unroll
        for (int nt = 0; nt < 2; ++nt)
            b[nt] = *(const short8*)(&W2t[(n0 + nt * 16 + lr) * 128 + kb]);
        #pragma unroll
        for (int mt = 0; mt < 2; ++mt)
            #pragma unroll
            for (int nt = 0; nt < 2; ++nt)
                acc2[mt][nt] = __builtin_amdgcn_mfma_f32_16x16x32_bf16(
                    a[mt], b[nt], acc2[mt][nt], 0, 0, 0);
    }
    {
        float bias[2] = { b2[n0 + lr], b2[n0 + 16 + lr] };
        #pragma unroll
        for (int mt = 0; mt < 2; ++mt)
            #pragma unroll
            for (int r = 0; r < 4; ++r) {
                const int m   = mt * 16 + q * 4 + r;
                const int dst = sDst[m];
                float* row = &mi[(size_t)dst * 128];
                #pragma unroll
                for (int nt = 0; nt < 2; ++nt)
                    atomicAdd(&row[n0 + nt * 16 + lr], acc2[mt][nt][r] + bias[nt]);
            }
    }
}

// ---- node kernel: stages h from pre-converted hbf when available ----
template <bool USEHBF>
__global__ __launch_bounds__(256, 8)
void node_mfma(const float* __restrict__ h,
               const unsigned short* __restrict__ hbf,
               const float* __restrict__ mi,
               const unsigned short* __restrict__ W1t,
               const float* __restrict__ b1,
               const unsigned short* __restrict__ W2t,
               const float* __restrict__ b2,
               float* __restrict__ out)
{
    __shared__ unsigned short sMem[32 * NK];

    const int tid = threadIdx.x;
    const int g0  = blockIdx.x * 32;

    const float4* h4   = (const float4*)h;
    const short8* hbf8 = (const short8*)hbf;
    const float4* mi4  = (const float4*)mi;
    if (USEHBF) {
        // h half: 32 rows x 16 short8 copies
        #pragma unroll
        for (int it = 0; it < 2; ++it) {
            const int idx = tid + it * 256;
            const int n  = idx >> 4;
            const int c  = idx & 15;
            const int gn = g0 + n;
            short8 v = (short8){0,0,0,0,0,0,0,0};
            if (gn < N_TOTAL) v = hbf8[(size_t)gn * 16 + c];
            *(short8*)(&sMem[n * NK + c * 8]) = v;
        }
        // mi half: 32 rows x 32 float4-converts
        #pragma unroll
        for (int it = 0; it < 4; ++it) {
            const int idx = tid + it * 256;
            const int n  = idx >> 5;
            const int c  = idx & 31;
            const int gn = g0 + n;
            float4 v = make_float4(0.f, 0.f, 0.f, 0.f);
            if (gn < N_TOTAL) v = mi4[(size_t)gn * 32 + c];
            unsigned short* p = &sMem[n * NK + 128 + c * 4];
            p[0] = f2bf(v.x); p[1] = f2bf(v.y); p[2] = f2bf(v.z); p[3] = f2bf(v.w);
        }
    } else {
        #pragma unroll
        for (int it = 0; it < 8; ++it) {
            const int idx = tid + it * 256;
            const int n  = idx >> 6;
            const int c  = idx & 63;
            const int gn = g0 + n;
            float4 v = make_float4(0.f, 0.f, 0.f, 0.f);
            if (gn < N_TOTAL)
                v = (c < 32) ? h4[(size_t)gn * 32 + c] : mi4[(size_t)gn * 32 + (c - 32)];
            unsigned short* p = &sMem[n * NK + c * 4];
            p[0] = f2bf(v.x); p[1] = f2bf(v.y); p[2] = f2bf(v.z); p[3] = f2bf(v.w);
        }
    }
    __syncthreads();

    const int lane = tid & 63;
    const int w    = tid >> 6;
    const int q    = lane >> 4;
    const int lr   = lane & 15;
    const int n0   = w * 32;

    floatx4 acc[2][2];
    #pragma unroll
    for (int mt = 0; mt < 2; ++mt)
        #pragma unroll
        for (int nt = 0; nt < 2; ++nt)
            acc[mt][nt] = (floatx4){0.f, 0.f, 0.f, 0.f};
    #pragma unroll
    for (int ks = 0; ks < 8; ++ks) {
        const int kb = ks * 32 + q * 8;
        short8 a[2], b[2];
        #pragma unroll
        for (int mt = 0; mt < 2; ++mt)
            a[mt] = *(const short8*)(&sMem[(mt * 16 + lr) * NK + kb]);
        #pragma unroll
        for (int nt = 0; nt < 2; ++nt)
            b[nt] = *(const short8*)(&W1t[(n0 + nt * 16 + lr) * 256 + kb]);
        #pragma unroll
        for (int mt = 0; mt < 2; ++mt)
            #pragma unroll
            for (int nt = 0; nt < 2; ++nt)
                acc[mt][nt] = __builtin_amdgcn_mfma_f32_16x16x32_bf16(
                    a[mt], b[nt], acc[mt][nt], 0, 0, 0);
    }
    __syncthreads();
    {
        float bias[2] = { b1[n0 + lr], b1[n0 + 16 + lr] };
        #pragma unroll
        for (int mt = 0; mt < 2; ++mt)
            #pragma unroll
            for (int nt = 0; nt < 2; ++nt)
                #pragma unroll
                for (int r = 0; r < 4; ++r) {
                    float v = fmaxf(acc[mt][nt][r] + bias[nt], 0.f);
                    sMem[(mt * 16 + q * 4 + r) * HK + n0 + nt * 16 + lr] = f2bf(v);
                }
    }
    __syncthreads();
    floatx4 acc2[2][2];
    #pragma unroll
    for (int mt = 0; mt < 2; ++mt)
        #pragma unroll
        for (int nt = 0; nt < 2; ++nt)
            acc2[mt][nt] = (floatx4){0.f, 0.f, 0.f, 0.f};
    #pragma unroll
    for (int ks = 0; ks < 4; ++ks) {
        const int kb = ks * 32 + q * 8;
        short8 a[2], b[2];
        #pragma unroll
        for (int mt = 0; mt < 2; ++mt)
            a[mt] = *(const short8*)(&sMem[(mt * 16 + lr) * HK + kb]);
        #pragma unroll
        for (int nt = 0; nt < 2; ++nt)
            b[nt] = *(const short8*)(&W2t[(n0 + nt * 16 + lr) * 128 + kb]);
        #pragma unroll
        for (int mt = 0; mt < 2; ++mt)
            #pragma unroll
            for (int nt = 0; nt < 2; ++nt)
                acc2[mt][nt] = __builtin_amdgcn_mfma_f32_16x16x32_bf16(
                    a[mt], b[nt], acc2[mt][nt], 0, 0, 0);
    }
    {
        float bias[2] = { b2[n0 + lr], b2[n0 + 16 + lr] };
        #pragma unroll
        for (int mt = 0; mt < 2; ++mt)
            #pragma unroll
            for (int r = 0; r < 4; ++r) {
                const int gm = g0 + mt * 16 + q * 4 + r;
                if (gm < N_TOTAL) {
                    #pragma unroll
                    for (int nt = 0; nt < 2; ++nt)
                        out[(size_t)gm * 128 + n0 + nt * 16 + lr] =
                            acc2[mt][nt][r] + bias[nt];
                }
            }
    }
}

extern "C" void kernel_launch(void* const* d_in, const int* in_sizes, int n_in,
                              void* d_out, int out_size, void* d_ws, size_t ws_size,
                              hipStream_t stream) {
    const float* h   = (const float*)d_in[0];
    const int*   ei  = (const int*)d_in[1];
    const float* ea  = (const float*)d_in[2];
    const float* We1 = (const float*)d_in[3];
    const float* be1 = (const float*)d_in[4];
    const float* We2 = (const float*)d_in[5];
    const float* be2 = (const float*)d_in[6];
    const float* Wh1 = (const float*)d_in[7];
    const float* bh1 = (const float*)d_in[8];
    const float* Wh2 = (const float*)d_in[9];
    const float* bh2 = (const float*)d_in[10];
    float* out = (float*)d_out;

    const size_t szMi   = (size_t)N_TOTAL * 128 * sizeof(float);
    const size_t szW1t  = 128 * 288 * 2;
    const size_t szW2t  = 128 * 128 * 2;
    const size_t szWh1t = 128 * 256 * 2;
    const size_t szWh2t = 128 * 128 * 2;
    const size_t szHbf  = (size_t)N_TOTAL * 128 * 2;
    const size_t szPerm = (size_t)E_TOTAL * 4;
    const size_t szHist = (size_t)NBINS * 4;

    const size_t offW1t  = szMi;
    const size_t offW2t  = offW1t + szW1t;
    const size_t offWh1t = offW2t + szW2t;
    const size_t offWh2t = offWh1t + szWh1t;
    const size_t offHbf  = offWh2t + szWh2t;
    const size_t offPerm = offHbf + szHbf;
    const size_t offHist = offPerm + szPerm;
    const size_t offCur  = offHist + szHist;
    const size_t offP1   = offCur + szHist;
    const size_t offP2   = offP1 + 1024;
    const size_t needFull = offP2 + 1024;
    const size_t needCvt  = offPerm;

    char* wsb = (char*)d_ws;
    float* mi = (float*)wsb;
    unsigned short* W1t  = (unsigned short*)(wsb + offW1t);
    unsigned short* W2t  = (unsigned short*)(wsb + offW2t);
    unsigned short* Wh1t = (unsigned short*)(wsb + offWh1t);
    unsigned short* Wh2t = (unsigned short*)(wsb + offWh2t);
    unsigned short* hbf  = (unsigned short*)(wsb + offHbf);
    int* perm    = (int*)(wsb + offPerm);
    int* hist    = (int*)(wsb + offHist);
    int* cursor  = (int*)(wsb + offCur);
    int* partial = (int*)(wsb + offP1);
    int* poff    = (int*)(wsb + offP2);

    const int full   = (ws_size >= needFull) ? 1 : 0;
    const int do_cvt = (ws_size >= needCvt + szHbf) ? 1 : 0;

    prep<<<9971, 256, 0, stream>>>(We1, We2, Wh1, Wh2, W1t, W2t, Wh1t, Wh2t,
                                   h, hbf, do_cvt, full, mi, hist);

    if (full) {
        k_hist<<<E_TOTAL / 256, 256, 0, stream>>>(ei, hist);
        k_scan1<<<NBINS / 256, 256, 0, stream>>>(hist, partial);
        k_scan2<<<1, 256, 0, stream>>>(partial, poff);
        k_scan3<<<NBINS / 256, 256, 0, stream>>>(hist, poff, cursor);
        k_scatter<<<E_TOTAL / 256, 256, 0, stream>>>(ei, cursor, perm);
        edge_mfma_sorted<<<E_TOTAL / 64, 256, 0, stream>>>(
            hbf, ei, ea, perm, W1t, be1, W2t, be2, mi);
        node_mfma<true><<<(N_TOTAL + 31) / 32, 256, 0, stream>>>(
            h, hbf, mi, Wh1t, bh1, Wh2t, bh2, out);
    } else if (do_cvt) {
        edge_mfma_flat<true><<<E_TOTAL / 32, 256, 0, stream>>>(
            h, hbf, ei, ea, W1t, be1, W2t, be2, mi);
        node_mfma<true><<<(N_TOTAL + 31) / 32, 256, 0, stream>>>(
            h, hbf, mi, Wh1t, bh1, Wh2t, bh2, out);
    } else {
        edge_mfma_flat<false><<<E_TOTAL / 32, 256, 0, stream>>>(
            h, nullptr, ei, ea, W1t, be1, W2t, be2, mi);
        node_mfma<false><<<(N_TOTAL + 31) / 32, 256, 0, stream>>>(
            h, nullptr, mi, Wh1t, bh1, Wh2t, bh2, out);
    }
    (void)in_sizes; (void)n_in; (void)out_size;
}